// Round 5
// baseline (9069.271 us; speedup 1.0000x reference)
//
#include <hip/hip_runtime.h>

#define SEQ  4096
#define NB   64
#define NI   64
#define NH   256

typedef short  bf16x8 __attribute__((ext_vector_type(8)));
typedef short  bf16x4 __attribute__((ext_vector_type(4)));
typedef float  f32x4  __attribute__((ext_vector_type(4)));

__device__ __forceinline__ unsigned short f2bf(float f) {
    union { float f; unsigned u; } v; v.f = f;
    return (unsigned short)((v.u + 0x7fffu + ((v.u >> 16) & 1u)) >> 16);
}
__device__ __forceinline__ float bflo(int p) {
    union { int i; float f; } u; u.i = p << 16; return u.f;
}
__device__ __forceinline__ float bfhi(int p) {
    union { int i; float f; } u; u.i = p & 0xffff0000; return u.f;
}
__device__ __forceinline__ float fast_rcp(float x) { return __builtin_amdgcn_rcpf(x); }
__device__ __forceinline__ float sigm(float x) { return fast_rcp(1.f + __expf(-x)); }
// clamp-free tanh: 2/(1+e^{-2y}) - 1.  y->+inf: e->0 -> +1; y->-inf: e->inf -> rcp->0 -> -1.
__device__ __forceinline__ float tanh_(float y) {
    float e = __expf(-2.f * y);
    return fmaf(2.f, fast_rcp(1.f + e), -1.f);
}
__device__ __forceinline__ f32x4 mfma16(bf16x8 a, bf16x8 b, f32x4 c) {
    return __builtin_amdgcn_mfma_f32_16x16x32_bf16(a, b, c, 0, 0, 0);
}
__device__ __forceinline__ bf16x8 ldfrag(const float* p) {
    float4 a = *(const float4*)p;
    float4 b = *(const float4*)(p + 4);
    bf16x8 r;
    r[0] = (short)f2bf(a.x); r[1] = (short)f2bf(a.y);
    r[2] = (short)f2bf(a.z); r[3] = (short)f2bf(a.w);
    r[4] = (short)f2bf(b.x); r[5] = (short)f2bf(b.y);
    r[6] = (short)f2bf(b.z); r[7] = (short)f2bf(b.w);
    return r;
}

// ============ xg precompute: LDS-free, barrier-free =========================
__global__ __launch_bounds__(1024) void xg_pre(
        const float* __restrict__ x, const float* __restrict__ w_ih,
        const float* __restrict__ b_ih, const float* __restrict__ b_hh,
        short* __restrict__ xg, size_t plane, int t0, int ns)
{
    const int tid = threadIdx.x, wv = tid >> 6, lane = tid & 63;
    const int nn = lane & 15, q = lane >> 4;
    const int jb = wv;

    bf16x8 w[3][2];
    float bias[3];
    #pragma unroll
    for (int g = 0; g < 3; ++g) {
        const int row = g * NH + jb * 16 + nn;
        w[g][0] = ldfrag(w_ih + row * NI + q * 8);
        w[g][1] = ldfrag(w_ih + row * NI + 32 + q * 8);
        bias[g] = b_ih[row] + (g < 2 ? b_hh[row] : 0.f);
    }

    const int NT = ns * 4;                       // 16-row tiles in chunk
    for (int rt = blockIdx.x; rt < NT; rt += gridDim.x) {
        const float* xr = x + ((size_t)t0 * NB + (size_t)rt * 16 + nn) * NI + q * 8;
        bf16x8 a0 = ldfrag(xr);
        bf16x8 a1 = ldfrag(xr + 32);
        #pragma unroll
        for (int g = 0; g < 3; ++g) {
            f32x4 acc = {0.f, 0.f, 0.f, 0.f};
            acc = mfma16(a0, w[g][0], acc);
            acc = mfma16(a1, w[g][1], acc);
            bf16x4 v;
            #pragma unroll
            for (int m = 0; m < 4; ++m) v[m] = (short)f2bf(acc[m] + bias[g]);
            *(bf16x4*)(xg + (size_t)g * plane +
                       (((size_t)rt * 16 + jb) * 64 + lane) * 4) = v;
        }
    }
}

// ============ recurrent kernel ==============================================
// Round-4 structure (proven 4297us) + two LDS-port cuts (the established
// binding resource: ~270KB/step/CU read+write vs 2510cyc step @ ~110B/cyc):
//  1. wn chunks 6-7 cached in registers (+8 regs): wn LDS stream 128->96KB.
//     (Full wn-in-regs is infeasible: R3 showed 96+~35 regs > 128 cap.)
//  2. fcwl reads predicated to nn==0 lanes (B-tile is 15/16 zeros): the DS
//     port serves 64B instead of 1KB per read.
// Lessons held: xg consumed AFTER the MFMA chain (R2); 16 waves / 4 per SIMD
// for phase overlap (R1); clamp-free tanh + bhn-in-C-init are free (R4).
// LDS: wlds 96K | abuf 16K | fcwl 8K | oring 4K = 124 KB.
__global__ __launch_bounds__(1024, 4) void gru_rec(
        const short* __restrict__ xg, size_t plane,
        const float* __restrict__ w_hh,
        const float* __restrict__ b_hh,
        const float* __restrict__ fc_w,
        const float* __restrict__ fc_b,
        float* __restrict__ out,
        float* __restrict__ hcar,
        int t0, int ns)
{
    __shared__ short wlds[49152];    // n-gate W_hh: 16 jb x 6 chunks x 512
    __shared__ short abuf[8192];     // h staging, 2 x 8 chunks x 512
    __shared__ short fcwl[4096];     // fc_w B-frags (col 0 only), 8 x 512
    __shared__ float oring[1024];    // out ring, 2 x 32 steps x 16 batch

    const int tid = threadIdx.x, wv = tid >> 6, lane = tid & 63;
    const int nn = lane & 15, q = lane >> 4;
    const int bc = blockIdx.x, bbase = bc * 16;

    // ---- one-time staging ----
    bf16x8 wr[8], wz[8];
    #pragma unroll
    for (int c = 0; c < 8; ++c)
        wr[c] = ldfrag(w_hh + (0 * NH + wv * 16 + nn) * NH + c * 32 + q * 8);
    #pragma unroll
    for (int c = 0; c < 8; ++c)
        wz[c] = ldfrag(w_hh + (1 * NH + wv * 16 + nn) * NH + c * 32 + q * 8);
    #pragma unroll
    for (int c = 0; c < 6; ++c) {    // chunks 0-5 -> LDS
        bf16x8 f = ldfrag(w_hh + (2 * NH + wv * 16 + nn) * NH + c * 32 + q * 8);
        *(bf16x8*)(wlds + (wv * 6 + c) * 512 + lane * 8) = f;
    }
    // chunks 6-7 -> registers (persistent)
    bf16x8 wn6 = ldfrag(w_hh + (2 * NH + wv * 16 + nn) * NH + 6 * 32 + q * 8);
    bf16x8 wn7 = ldfrag(w_hh + (2 * NH + wv * 16 + nn) * NH + 7 * 32 + q * 8);
    if (wv < 8) {                    // fc B-frag: col nn==0 = fc_w, else 0
        bf16x8 f = 0;
        if (nn == 0) f = ldfrag(fc_w + wv * 32 + q * 8);
        *(bf16x8*)(fcwl + wv * 512 + lane * 8) = f;
    }
    const float bhn = b_hh[2 * NH + wv * 16 + nn];
    const float fcb = fc_b[0];

    // ---- h init ----
    f32x4 hp = {0.f, 0.f, 0.f, 0.f};
    if (t0 == 0) {
        ((int4*)abuf)[tid & 511] = make_int4(0, 0, 0, 0);
    } else {
        #pragma unroll
        for (int m = 0; m < 4; ++m)
            hp[m] = hcar[(size_t)(bbase + q * 4 + m) * NH + wv * 16 + nn];
        const int f = tid * 4, b = f >> 8, k0 = f & 255;
        float4 v = *(const float4*)(hcar + (size_t)(bbase + b) * NH + k0);
        bf16x4 s; s[0] = (short)f2bf(v.x); s[1] = (short)f2bf(v.y);
        s[2] = (short)f2bf(v.z); s[3] = (short)f2bf(v.w);
        *(bf16x4*)(abuf + (k0 >> 5) * 512 + (((k0 >> 3) & 3) * 16 + b) * 8 + (k0 & 7)) = s;
    }

    const int j = wv * 16 + nn;
    const int koff = (j >> 5) * 512 + ((j >> 3) & 3) * 128 + (j & 7) + q * 32;
    const short* xgp = xg + ((size_t)(bc * 16 + wv) * 64 + lane) * 4;
    __syncthreads();

    for (int t = 0; t < ns; ++t) {
        const int cur = t & 1, nxt = cur ^ 1;

        int2 gx = *(const int2*)(xgp);
        int2 gz = *(const int2*)(xgp + plane);
        int2 gn = *(const int2*)(xgp + 2 * plane);
        xgp += 16384;

        // out flush, once per 32 steps (slots all >=1 barrier old)
        if ((t & 31) == 1 && t >= 33 && tid < 512) {
            const int s0 = t - 33;
            out[((size_t)(t0 + s0 + (tid >> 4))) * NB + bbase + (tid & 15)] =
                oring[(((s0 >> 5) & 1) << 9) + (tid >> 4) * 16 + (tid & 15)];
        }

        const bool isfc = (t > 0) && (wv == (t & 15));
        f32x4 ar = {0.f,0.f,0.f,0.f}, az = {0.f,0.f,0.f,0.f};
        f32x4 an = { bhn, bhn, bhn, bhn };   // b_hh(n) folded into C-init
        f32x4 afc = {0.f,0.f,0.f,0.f};
        const short* ab = abuf + cur * 4096;
        #pragma unroll
        for (int c = 0; c < 8; ++c) {
            bf16x8 av = *(const bf16x8*)(ab + c * 512 + lane * 8);
            ar = mfma16(av, wr[c], ar);
            az = mfma16(av, wz[c], az);
            bf16x8 wnf = (c < 6) ? *(const bf16x8*)(wlds + (wv * 6 + c) * 512 + lane * 8)
                                 : (c == 6 ? wn6 : wn7);
            an = mfma16(av, wnf, an);
            if (isfc) {   // rotating wave: FC(h_{t-1}) rides on the same av
                bf16x8 ff = 0;
                if (nn == 0)   // only col 0 is nonzero: 4-lane read, not 64
                    ff = *(const bf16x8*)(fcwl + c * 512 + lane * 8);
                afc = mfma16(av, ff, afc);
            }
        }
        if (isfc && nn == 0) {
            const int s = t - 1;
            f32x4 v;
            #pragma unroll
            for (int m = 0; m < 4; ++m) v[m] = afc[m] + fcb;
            *(f32x4*)(oring + (((s >> 5) & 1) << 9) + ((s & 31) << 4) + q * 4) = v;
        }

        const float xr4[4] = { bflo(gx.x), bfhi(gx.x), bflo(gx.y), bfhi(gx.y) };
        const float xz4[4] = { bflo(gz.x), bfhi(gz.x), bflo(gz.y), bfhi(gz.y) };
        const float xn4[4] = { bflo(gn.x), bfhi(gn.x), bflo(gn.y), bfhi(gn.y) };

        short* hw = abuf + nxt * 4096 + koff;
        #pragma unroll
        for (int m = 0; m < 4; ++m) {
            float r_ = sigm(ar[m] + xr4[m]);           // b_hh(r,z) folded upstream
            float z_ = sigm(az[m] + xz4[m]);
            float n_ = tanh_(fmaf(r_, an[m], xn4[m])); // an = bhn + sum(h*wn)
            float h_ = fmaf(z_, hp[m] - n_, n_);
            hp[m] = h_;
            hw[m * 8] = (short)f2bf(h_);
        }
        __syncthreads();   // single per-step barrier
    }

    // ---- tail: FC for step ns-1, flush last 32, h carry ----
    if (wv == 0) {
        const short* ab = abuf + (ns & 1) * 4096;
        f32x4 afc = {0.f, 0.f, 0.f, 0.f};
        #pragma unroll
        for (int c = 0; c < 8; ++c) {
            bf16x8 ff = 0;
            if (nn == 0) ff = *(const bf16x8*)(fcwl + c * 512 + lane * 8);
            afc = mfma16(*(const bf16x8*)(ab + c * 512 + lane * 8), ff, afc);
        }
        if (nn == 0) {
            const int s = ns - 1;
            f32x4 v;
            #pragma unroll
            for (int m = 0; m < 4; ++m) v[m] = afc[m] + fcb;
            *(f32x4*)(oring + (((s >> 5) & 1) << 9) + ((s & 31) << 4) + q * 4) = v;
        }
    }
    __syncthreads();
    if (tid < 512) {
        const int s0 = ns - 32;
        out[((size_t)(t0 + s0 + (tid >> 4))) * NB + bbase + (tid & 15)] =
            oring[(((s0 >> 5) & 1) << 9) + (tid >> 4) * 16 + (tid & 15)];
    }
    #pragma unroll
    for (int m = 0; m < 4; ++m)
        hcar[(size_t)(bbase + q * 4 + m) * NH + wv * 16 + nn] = hp[m];
}

extern "C" void kernel_launch(void* const* d_in, const int* in_sizes, int n_in,
                              void* d_out, int out_size, void* d_ws, size_t ws_size,
                              hipStream_t stream) {
    (void)in_sizes; (void)n_in; (void)out_size;
    const float* x    = (const float*)d_in[0];
    const float* w_ih = (const float*)d_in[1];
    const float* w_hh = (const float*)d_in[2];
    const float* b_ih = (const float*)d_in[3];
    const float* b_hh = (const float*)d_in[4];
    const float* fc_w = (const float*)d_in[5];
    const float* fc_b = (const float*)d_in[6];
    float* out  = (float*)d_out;
    float* hcar = (float*)d_ws;                       // 64 KB h carry
    short* xg   = (short*)((char*)d_ws + 65536);      // 3 gate planes

    const size_t per_step = (size_t)NB * 3 * NH * 2;  // 98304 B / step
    long avail = (long)ws_size - 65536;
    int spc = 64;
    if (avail >= (long)per_step * 64) {
        spc = (int)((avail / (long)per_step) / 64) * 64;
        if (spc > SEQ) spc = SEQ;
    }
    for (int t0 = 0; t0 < SEQ; t0 += spc) {
        int ns = (SEQ - t0 < spc) ? (SEQ - t0) : spc;
        size_t plane = (size_t)spc * 16384;           // shorts per gate plane
        xg_pre<<<dim3(2048), dim3(1024), 0, stream>>>(x, w_ih, b_ih, b_hh,
                                                      xg, plane, t0, ns);
        gru_rec<<<dim3(4), dim3(1024), 0, stream>>>(xg, plane, w_hh, b_hh,
                                                    fc_w, fc_b, out, hcar,
                                                    t0, ns);
    }
}

// Round 7
// 6848.002 us; speedup vs baseline: 1.3244x; 1.3244x over previous
//
#include <hip/hip_runtime.h>

#define SEQ  4096
#define NB   64
#define NI   64
#define NH   256

typedef short  bf16x8 __attribute__((ext_vector_type(8)));
typedef short  bf16x4 __attribute__((ext_vector_type(4)));
typedef float  f32x4  __attribute__((ext_vector_type(4)));

__device__ __forceinline__ unsigned short f2bf(float f) {
    union { float f; unsigned u; } v; v.f = f;
    return (unsigned short)((v.u + 0x7fffu + ((v.u >> 16) & 1u)) >> 16);
}
__device__ __forceinline__ float bflo(int p) {
    union { int i; float f; } u; u.i = p << 16; return u.f;
}
__device__ __forceinline__ float bfhi(int p) {
    union { int i; float f; } u; u.i = p & 0xffff0000; return u.f;
}
__device__ __forceinline__ float fast_rcp(float x) { return __builtin_amdgcn_rcpf(x); }
__device__ __forceinline__ float sigm(float x) { return fast_rcp(1.f + __expf(-x)); }
// clamp-free tanh: 2/(1+e^{-2y}) - 1.  y->+inf: e->0 -> +1; y->-inf: e->inf -> rcp->0 -> -1.
__device__ __forceinline__ float tanh_(float y) {
    float e = __expf(-2.f * y);
    return fmaf(2.f, fast_rcp(1.f + e), -1.f);
}
__device__ __forceinline__ f32x4 mfma16(bf16x8 a, bf16x8 b, f32x4 c) {
    return __builtin_amdgcn_mfma_f32_16x16x32_bf16(a, b, c, 0, 0, 0);
}
__device__ __forceinline__ bf16x8 ldfrag(const float* p) {
    float4 a = *(const float4*)p;
    float4 b = *(const float4*)(p + 4);
    bf16x8 r;
    r[0] = (short)f2bf(a.x); r[1] = (short)f2bf(a.y);
    r[2] = (short)f2bf(a.z); r[3] = (short)f2bf(a.w);
    r[4] = (short)f2bf(b.x); r[5] = (short)f2bf(b.y);
    r[6] = (short)f2bf(b.z); r[7] = (short)f2bf(b.w);
    return r;
}

// ============ xg precompute + one-time wn67 bf16 scratch ====================
__global__ __launch_bounds__(1024) void xg_pre(
        const float* __restrict__ x, const float* __restrict__ w_ih,
        const float* __restrict__ w_hh,
        const float* __restrict__ b_ih, const float* __restrict__ b_hh,
        short* __restrict__ xg, short* __restrict__ wnsc,
        size_t plane, int t0, int ns)
{
    const int tid = threadIdx.x, wv = tid >> 6, lane = tid & 63;
    const int nn = lane & 15, q = lane >> 4;
    const int jb = wv;

    // one-time: bf16-converted n-gate W_hh chunks 6-7 -> global scratch.
    // SIZE: 16 wv x 64 lanes x 16 shorts x 2B = 32768 B (R6 bug: was sized
    // 16KB and overran into xg plane 0 -> absmax 0.55).
    if (t0 == 0 && blockIdx.x == 0) {
        bf16x8 f6 = ldfrag(w_hh + (2 * NH + wv * 16 + nn) * NH + 6 * 32 + q * 8);
        bf16x8 f7 = ldfrag(w_hh + (2 * NH + wv * 16 + nn) * NH + 7 * 32 + q * 8);
        *(bf16x8*)(wnsc + ((size_t)wv * 64 + lane) * 16)     = f6;
        *(bf16x8*)(wnsc + ((size_t)wv * 64 + lane) * 16 + 8) = f7;
    }

    bf16x8 w[3][2];
    float bias[3];
    #pragma unroll
    for (int g = 0; g < 3; ++g) {
        const int row = g * NH + jb * 16 + nn;
        w[g][0] = ldfrag(w_ih + row * NI + q * 8);
        w[g][1] = ldfrag(w_ih + row * NI + 32 + q * 8);
        bias[g] = b_ih[row] + (g < 2 ? b_hh[row] : 0.f);
    }

    const int NT = ns * 4;                       // 16-row tiles in chunk
    for (int rt = blockIdx.x; rt < NT; rt += gridDim.x) {
        const float* xr = x + ((size_t)t0 * NB + (size_t)rt * 16 + nn) * NI + q * 8;
        bf16x8 a0 = ldfrag(xr);
        bf16x8 a1 = ldfrag(xr + 32);
        #pragma unroll
        for (int g = 0; g < 3; ++g) {
            f32x4 acc = {0.f, 0.f, 0.f, 0.f};
            acc = mfma16(a0, w[g][0], acc);
            acc = mfma16(a1, w[g][1], acc);
            bf16x4 v;
            #pragma unroll
            for (int m = 0; m < 4; ++m) v[m] = (short)f2bf(acc[m] + bias[g]);
            *(bf16x4*)(xg + (size_t)g * plane +
                       (((size_t)rt * 16 + jb) * 64 + lane) * 4) = v;
        }
    }
}

// ============ recurrent kernel ==============================================
// R4 structure (proven 4297us) + ONE change: wn chunks 6-7 stream from the
// VMEM/L2 path instead of the LDS port (the established binding resource,
// ~272KB/step/CU). Their addresses are loop-invariant and the 32KB bf16
// scratch is permanently L2-hot; the 2 global_load_dwordx4 are issued at
// loop TOP and consumed at the END of the MFMA chain (~600cyc slack >> L2
// latency; nothing drains vmcnt in between -- respects the R2 lesson).
// LDS traffic 272 -> 240 KB/step. fcwl read UNCONDITIONAL (R5 lesson: a
// divergent ds_read feeding an MFMA serializes the chain; with a per-step
// barrier one slow wave taxes all).
// LDS: wlds 96K | abuf 16K | fcwl 8K | oring 4K = 124 KB.
__global__ __launch_bounds__(1024, 4) void gru_rec(
        const short* __restrict__ xg, size_t plane,
        const float* __restrict__ w_hh,
        const float* __restrict__ b_hh,
        const float* __restrict__ fc_w,
        const float* __restrict__ fc_b,
        const short* __restrict__ wnsc,
        float* __restrict__ out,
        float* __restrict__ hcar,
        int t0, int ns)
{
    __shared__ short wlds[49152];    // n-gate W_hh: 16 jb x 6 chunks x 512
    __shared__ short abuf[8192];     // h staging, 2 x 8 chunks x 512
    __shared__ short fcwl[4096];     // fc_w B-frags (col 0 only), 8 x 512
    __shared__ float oring[1024];    // out ring, 2 x 32 steps x 16 batch

    const int tid = threadIdx.x, wv = tid >> 6, lane = tid & 63;
    const int nn = lane & 15, q = lane >> 4;
    const int bc = blockIdx.x, bbase = bc * 16;

    // ---- one-time staging ----
    bf16x8 wr[8], wz[8];
    #pragma unroll
    for (int c = 0; c < 8; ++c)
        wr[c] = ldfrag(w_hh + (0 * NH + wv * 16 + nn) * NH + c * 32 + q * 8);
    #pragma unroll
    for (int c = 0; c < 8; ++c)
        wz[c] = ldfrag(w_hh + (1 * NH + wv * 16 + nn) * NH + c * 32 + q * 8);
    #pragma unroll
    for (int c = 0; c < 6; ++c) {    // chunks 0-5 -> LDS; 6-7 stream from L2
        bf16x8 f = ldfrag(w_hh + (2 * NH + wv * 16 + nn) * NH + c * 32 + q * 8);
        *(bf16x8*)(wlds + (wv * 6 + c) * 512 + lane * 8) = f;
    }
    if (wv < 8) {                    // fc B-frag: col nn==0 = fc_w, else 0
        bf16x8 f = 0;
        if (nn == 0) f = ldfrag(fc_w + wv * 32 + q * 8);
        *(bf16x8*)(fcwl + wv * 512 + lane * 8) = f;
    }
    const float bhn = b_hh[2 * NH + wv * 16 + nn];
    const float fcb = fc_b[0];
    const short* wnp = wnsc + ((size_t)wv * 64 + lane) * 16;  // loop-invariant

    // ---- h init ----
    f32x4 hp = {0.f, 0.f, 0.f, 0.f};
    if (t0 == 0) {
        ((int4*)abuf)[tid & 511] = make_int4(0, 0, 0, 0);
    } else {
        #pragma unroll
        for (int m = 0; m < 4; ++m)
            hp[m] = hcar[(size_t)(bbase + q * 4 + m) * NH + wv * 16 + nn];
        const int f = tid * 4, b = f >> 8, k0 = f & 255;
        float4 v = *(const float4*)(hcar + (size_t)(bbase + b) * NH + k0);
        bf16x4 s; s[0] = (short)f2bf(v.x); s[1] = (short)f2bf(v.y);
        s[2] = (short)f2bf(v.z); s[3] = (short)f2bf(v.w);
        *(bf16x4*)(abuf + (k0 >> 5) * 512 + (((k0 >> 3) & 3) * 16 + b) * 8 + (k0 & 7)) = s;
    }

    const int j = wv * 16 + nn;
    const int koff = (j >> 5) * 512 + ((j >> 3) & 3) * 128 + (j & 7) + q * 32;
    const short* xgp = xg + ((size_t)(bc * 16 + wv) * 64 + lane) * 4;
    __syncthreads();

    for (int t = 0; t < ns; ++t) {
        const int cur = t & 1, nxt = cur ^ 1;

        // wn67 stream from L2 scratch: issued first, consumed at chain end
        bf16x8 wn6g = *(const bf16x8*)(wnp);
        bf16x8 wn7g = *(const bf16x8*)(wnp + 8);

        int2 gx = *(const int2*)(xgp);
        int2 gz = *(const int2*)(xgp + plane);
        int2 gn = *(const int2*)(xgp + 2 * plane);
        xgp += 16384;

        // out flush, once per 32 steps (slots all >=1 barrier old)
        if ((t & 31) == 1 && t >= 33 && tid < 512) {
            const int s0 = t - 33;
            out[((size_t)(t0 + s0 + (tid >> 4))) * NB + bbase + (tid & 15)] =
                oring[(((s0 >> 5) & 1) << 9) + (tid >> 4) * 16 + (tid & 15)];
        }

        const bool isfc = (t > 0) && (wv == (t & 15));
        f32x4 ar = {0.f,0.f,0.f,0.f}, az = {0.f,0.f,0.f,0.f};
        f32x4 an = { bhn, bhn, bhn, bhn };   // b_hh(n) folded into C-init
        f32x4 afc = {0.f,0.f,0.f,0.f};
        const short* ab = abuf + cur * 4096;
        #pragma unroll
        for (int c = 0; c < 8; ++c) {
            bf16x8 av = *(const bf16x8*)(ab + c * 512 + lane * 8);
            ar = mfma16(av, wr[c], ar);
            az = mfma16(av, wz[c], az);
            bf16x8 wnf = (c < 6) ? *(const bf16x8*)(wlds + (wv * 6 + c) * 512 + lane * 8)
                                 : (c == 6 ? wn6g : wn7g);
            an = mfma16(av, wnf, an);
            if (isfc) {   // rotating wave: FC(h_{t-1}) rides on the same av
                bf16x8 ff = *(const bf16x8*)(fcwl + c * 512 + lane * 8);
                afc = mfma16(av, ff, afc);
            }
        }
        if (isfc && nn == 0) {
            const int s = t - 1;
            f32x4 v;
            #pragma unroll
            for (int m = 0; m < 4; ++m) v[m] = afc[m] + fcb;
            *(f32x4*)(oring + (((s >> 5) & 1) << 9) + ((s & 31) << 4) + q * 4) = v;
        }

        const float xr4[4] = { bflo(gx.x), bfhi(gx.x), bflo(gx.y), bfhi(gx.y) };
        const float xz4[4] = { bflo(gz.x), bfhi(gz.x), bflo(gz.y), bfhi(gz.y) };
        const float xn4[4] = { bflo(gn.x), bfhi(gn.x), bflo(gn.y), bfhi(gn.y) };

        short* hw = abuf + nxt * 4096 + koff;
        #pragma unroll
        for (int m = 0; m < 4; ++m) {
            float r_ = sigm(ar[m] + xr4[m]);           // b_hh(r,z) folded upstream
            float z_ = sigm(az[m] + xz4[m]);
            float n_ = tanh_(fmaf(r_, an[m], xn4[m])); // an = bhn + sum(h*wn)
            float h_ = fmaf(z_, hp[m] - n_, n_);
            hp[m] = h_;
            hw[m * 8] = (short)f2bf(h_);
        }
        __syncthreads();   // single per-step barrier
    }

    // ---- tail: FC for step ns-1, flush last 32, h carry ----
    if (wv == 0) {
        const short* ab = abuf + (ns & 1) * 4096;
        f32x4 afc = {0.f, 0.f, 0.f, 0.f};
        #pragma unroll
        for (int c = 0; c < 8; ++c)
            afc = mfma16(*(const bf16x8*)(ab + c * 512 + lane * 8),
                         *(const bf16x8*)(fcwl + c * 512 + lane * 8), afc);
        if (nn == 0) {
            const int s = ns - 1;
            f32x4 v;
            #pragma unroll
            for (int m = 0; m < 4; ++m) v[m] = afc[m] + fcb;
            *(f32x4*)(oring + (((s >> 5) & 1) << 9) + ((s & 31) << 4) + q * 4) = v;
        }
    }
    __syncthreads();
    if (tid < 512) {
        const int s0 = ns - 32;
        out[((size_t)(t0 + s0 + (tid >> 4))) * NB + bbase + (tid & 15)] =
            oring[(((s0 >> 5) & 1) << 9) + (tid >> 4) * 16 + (tid & 15)];
    }
    #pragma unroll
    for (int m = 0; m < 4; ++m)
        hcar[(size_t)(bbase + q * 4 + m) * NH + wv * 16 + nn] = hp[m];
}

extern "C" void kernel_launch(void* const* d_in, const int* in_sizes, int n_in,
                              void* d_out, int out_size, void* d_ws, size_t ws_size,
                              hipStream_t stream) {
    (void)in_sizes; (void)n_in; (void)out_size;
    const float* x    = (const float*)d_in[0];
    const float* w_ih = (const float*)d_in[1];
    const float* w_hh = (const float*)d_in[2];
    const float* b_ih = (const float*)d_in[3];
    const float* b_hh = (const float*)d_in[4];
    const float* fc_w = (const float*)d_in[5];
    const float* fc_b = (const float*)d_in[6];
    float* out  = (float*)d_out;
    float* hcar = (float*)d_ws;                       // 64 KB h carry
    short* wnsc = (short*)((char*)d_ws + 65536);      // 32 KB wn67 bf16 scratch
    short* xg   = (short*)((char*)d_ws + 65536 + 32768);  // 3 gate planes

    const size_t per_step = (size_t)NB * 3 * NH * 2;  // 98304 B / step
    long avail = (long)ws_size - 65536 - 32768;
    int spc = 64;
    if (avail >= (long)per_step * 64) {
        spc = (int)((avail / (long)per_step) / 64) * 64;
        if (spc > SEQ) spc = SEQ;
    }
    for (int t0 = 0; t0 < SEQ; t0 += spc) {
        int ns = (SEQ - t0 < spc) ? (SEQ - t0) : spc;
        size_t plane = (size_t)spc * 16384;           // shorts per gate plane
        xg_pre<<<dim3(2048), dim3(1024), 0, stream>>>(x, w_ih, w_hh, b_ih, b_hh,
                                                      xg, wnsc, plane, t0, ns);
        gru_rec<<<dim3(4), dim3(1024), 0, stream>>>(xg, plane, w_hh, b_hh,
                                                    fc_w, fc_b, wnsc, out, hcar,
                                                    t0, ns);
    }
}

// Round 9
// 6725.594 us; speedup vs baseline: 1.3485x; 1.0182x over previous
//
#include <hip/hip_runtime.h>

#define SEQ  4096
#define NB   64
#define NI   64
#define NH   256

typedef short  bf16x8 __attribute__((ext_vector_type(8)));
typedef short  bf16x4 __attribute__((ext_vector_type(4)));
typedef float  f32x4  __attribute__((ext_vector_type(4)));
typedef float  f32x2  __attribute__((ext_vector_type(2)));

__device__ __forceinline__ unsigned short f2bf(float f) {
    union { float f; unsigned u; } v; v.f = f;
    return (unsigned short)((v.u + 0x7fffu + ((v.u >> 16) & 1u)) >> 16);
}
__device__ __forceinline__ float bflo(int p) {
    union { int i; float f; } u; u.i = p << 16; return u.f;
}
__device__ __forceinline__ float bfhi(int p) {
    union { int i; float f; } u; u.i = p & 0xffff0000; return u.f;
}
__device__ __forceinline__ float fast_rcp(float x) { return __builtin_amdgcn_rcpf(x); }
__device__ __forceinline__ float sigm(float x) { return fast_rcp(1.f + __expf(-x)); }
// clamp-free tanh: 2/(1+e^{-2y}) - 1 (saturates correctly at +-inf, no NaN path)
__device__ __forceinline__ float tanh_(float y) {
    float e = __expf(-2.f * y);
    return fmaf(2.f, fast_rcp(1.f + e), -1.f);
}
// packed bf16 convert (RNE) -- same rounding as f2bf, 1 inst for 2 values
__device__ __forceinline__ int cvtpk_bf16(float lo, float hi) {
    int r; asm("v_cvt_pk_bf16_f32 %0, %1, %2" : "=v"(r) : "v"(lo), "v"(hi));
    return r;
}
// two packed bf16 (lo16,hi16 of p) -> f32x2
__device__ __forceinline__ f32x2 bfup2(int p) {
    f32x2 r; r[0] = bflo(p); r[1] = bfhi(p); return r;
}
__device__ __forceinline__ f32x4 mfma16(bf16x8 a, bf16x8 b, f32x4 c) {
    return __builtin_amdgcn_mfma_f32_16x16x32_bf16(a, b, c, 0, 0, 0);
}
__device__ __forceinline__ bf16x8 ldfrag(const float* p) {
    float4 a = *(const float4*)p;
    float4 b = *(const float4*)(p + 4);
    bf16x8 r;
    r[0] = (short)f2bf(a.x); r[1] = (short)f2bf(a.y);
    r[2] = (short)f2bf(a.z); r[3] = (short)f2bf(a.w);
    r[4] = (short)f2bf(b.x); r[5] = (short)f2bf(b.y);
    r[6] = (short)f2bf(b.z); r[7] = (short)f2bf(b.w);
    return r;
}

// ============ xg precompute + one-time wn67 bf16 scratch ====================
__global__ __launch_bounds__(1024) void xg_pre(
        const float* __restrict__ x, const float* __restrict__ w_ih,
        const float* __restrict__ w_hh,
        const float* __restrict__ b_ih, const float* __restrict__ b_hh,
        short* __restrict__ xg, short* __restrict__ wnsc,
        size_t plane, int t0, int ns)
{
    const int tid = threadIdx.x, wv = tid >> 6, lane = tid & 63;
    const int nn = lane & 15, q = lane >> 4;
    const int jb = wv;

    // one-time: bf16-converted n-gate W_hh chunks 6-7 -> global scratch (32KB)
    if (t0 == 0 && blockIdx.x == 0) {
        bf16x8 f6 = ldfrag(w_hh + (2 * NH + wv * 16 + nn) * NH + 6 * 32 + q * 8);
        bf16x8 f7 = ldfrag(w_hh + (2 * NH + wv * 16 + nn) * NH + 7 * 32 + q * 8);
        *(bf16x8*)(wnsc + ((size_t)wv * 64 + lane) * 16)     = f6;
        *(bf16x8*)(wnsc + ((size_t)wv * 64 + lane) * 16 + 8) = f7;
    }

    bf16x8 w[3][2];
    float bias[3];
    #pragma unroll
    for (int g = 0; g < 3; ++g) {
        const int row = g * NH + jb * 16 + nn;
        w[g][0] = ldfrag(w_ih + row * NI + q * 8);
        w[g][1] = ldfrag(w_ih + row * NI + 32 + q * 8);
        bias[g] = b_ih[row] + (g < 2 ? b_hh[row] : 0.f);
    }

    const int NT = ns * 4;                       // 16-row tiles in chunk
    for (int rt = blockIdx.x; rt < NT; rt += gridDim.x) {
        const float* xr = x + ((size_t)t0 * NB + (size_t)rt * 16 + nn) * NI + q * 8;
        bf16x8 a0 = ldfrag(xr);
        bf16x8 a1 = ldfrag(xr + 32);
        #pragma unroll
        for (int g = 0; g < 3; ++g) {
            f32x4 acc = {0.f, 0.f, 0.f, 0.f};
            acc = mfma16(a0, w[g][0], acc);
            acc = mfma16(a1, w[g][1], acc);
            bf16x4 v;
            #pragma unroll
            for (int m = 0; m < 4; ++m) v[m] = (short)f2bf(acc[m] + bias[g]);
            *(bf16x4*)(xg + (size_t)g * plane +
                       (((size_t)rt * 16 + jb) * 64 + lane) * 4) = v;
        }
    }
}

// ============ recurrent kernel ==============================================
// R7 structure (proven 4300us, == R4) + packed-f32 nonlinearity:
// Ledger (R7): step 2510cyc/SIMD = MFMA/ds phase ~900 + elementwise ~1530,
// where 1530 = 4 lockstep waves x (~95 VALU x2cyc + 24 trans x8cyc) -- the
// VALU ISSUE PIPE during the nonlinearity is the binding resource (R7 proved
// LDS bytes are not: -32KB/step changed nothing).
// Fix: phase B rewritten in f32x2 -- LLVM legalizes <2 x float> arithmetic to
// VOP3P v_pk_{add,mul,fma}_f32 on gfx90a+ (2 elems/inst, full rate). Same op
// order as scalar version -> bit-identical math. Transcendentals stay scalar
// (no packed form). h->bf16 via v_cvt_pk_bf16_f32 (RNE, == f2bf rounding).
// Expected: phase-B VALU ~190->~100cyc/wave; trans 192 unchanged.
// (R8 bench was an infra failure -- container died before running; this is
// the same kernel resubmitted.)
// LDS: wlds 96K | abuf 16K | fcwl 8K | oring 4K = 124 KB.
__global__ __launch_bounds__(1024, 4) void gru_rec(
        const short* __restrict__ xg, size_t plane,
        const float* __restrict__ w_hh,
        const float* __restrict__ b_hh,
        const float* __restrict__ fc_w,
        const float* __restrict__ fc_b,
        const short* __restrict__ wnsc,
        float* __restrict__ out,
        float* __restrict__ hcar,
        int t0, int ns)
{
    __shared__ short wlds[49152];    // n-gate W_hh: 16 jb x 6 chunks x 512
    __shared__ short abuf[8192];     // h staging, 2 x 8 chunks x 512
    __shared__ short fcwl[4096];     // fc_w B-frags (col 0 only), 8 x 512
    __shared__ float oring[1024];    // out ring, 2 x 32 steps x 16 batch

    const int tid = threadIdx.x, wv = tid >> 6, lane = tid & 63;
    const int nn = lane & 15, q = lane >> 4;
    const int bc = blockIdx.x, bbase = bc * 16;

    // ---- one-time staging ----
    bf16x8 wr[8], wz[8];
    #pragma unroll
    for (int c = 0; c < 8; ++c)
        wr[c] = ldfrag(w_hh + (0 * NH + wv * 16 + nn) * NH + c * 32 + q * 8);
    #pragma unroll
    for (int c = 0; c < 8; ++c)
        wz[c] = ldfrag(w_hh + (1 * NH + wv * 16 + nn) * NH + c * 32 + q * 8);
    #pragma unroll
    for (int c = 0; c < 6; ++c) {    // chunks 0-5 -> LDS; 6-7 stream from L2
        bf16x8 f = ldfrag(w_hh + (2 * NH + wv * 16 + nn) * NH + c * 32 + q * 8);
        *(bf16x8*)(wlds + (wv * 6 + c) * 512 + lane * 8) = f;
    }
    if (wv < 8) {                    // fc B-frag: col nn==0 = fc_w, else 0
        bf16x8 f = 0;
        if (nn == 0) f = ldfrag(fc_w + wv * 32 + q * 8);
        *(bf16x8*)(fcwl + wv * 512 + lane * 8) = f;
    }
    const float bhn = b_hh[2 * NH + wv * 16 + nn];
    const float fcb = fc_b[0];
    const short* wnp = wnsc + ((size_t)wv * 64 + lane) * 16;  // loop-invariant

    // ---- h init ----
    f32x4 hp = {0.f, 0.f, 0.f, 0.f};
    if (t0 == 0) {
        ((int4*)abuf)[tid & 511] = make_int4(0, 0, 0, 0);
    } else {
        #pragma unroll
        for (int m = 0; m < 4; ++m)
            hp[m] = hcar[(size_t)(bbase + q * 4 + m) * NH + wv * 16 + nn];
        const int f = tid * 4, b = f >> 8, k0 = f & 255;
        float4 v = *(const float4*)(hcar + (size_t)(bbase + b) * NH + k0);
        bf16x4 s; s[0] = (short)f2bf(v.x); s[1] = (short)f2bf(v.y);
        s[2] = (short)f2bf(v.z); s[3] = (short)f2bf(v.w);
        *(bf16x4*)(abuf + (k0 >> 5) * 512 + (((k0 >> 3) & 3) * 16 + b) * 8 + (k0 & 7)) = s;
    }

    const int j = wv * 16 + nn;
    const int koff = (j >> 5) * 512 + ((j >> 3) & 3) * 128 + (j & 7) + q * 32;
    const short* xgp = xg + ((size_t)(bc * 16 + wv) * 64 + lane) * 4;
    __syncthreads();

    for (int t = 0; t < ns; ++t) {
        const int cur = t & 1, nxt = cur ^ 1;

        // wn67 stream from L2 scratch: issued first, consumed at chain end
        bf16x8 wn6g = *(const bf16x8*)(wnp);
        bf16x8 wn7g = *(const bf16x8*)(wnp + 8);

        int2 gx = *(const int2*)(xgp);
        int2 gz = *(const int2*)(xgp + plane);
        int2 gn = *(const int2*)(xgp + 2 * plane);
        xgp += 16384;

        // out flush, once per 32 steps (slots all >=1 barrier old)
        if ((t & 31) == 1 && t >= 33 && tid < 512) {
            const int s0 = t - 33;
            out[((size_t)(t0 + s0 + (tid >> 4))) * NB + bbase + (tid & 15)] =
                oring[(((s0 >> 5) & 1) << 9) + (tid >> 4) * 16 + (tid & 15)];
        }

        const bool isfc = (t > 0) && (wv == (t & 15));
        f32x4 ar = {0.f,0.f,0.f,0.f}, az = {0.f,0.f,0.f,0.f};
        f32x4 an = { bhn, bhn, bhn, bhn };   // b_hh(n) folded into C-init
        f32x4 afc = {0.f,0.f,0.f,0.f};
        const short* ab = abuf + cur * 4096;
        #pragma unroll
        for (int c = 0; c < 8; ++c) {
            bf16x8 av = *(const bf16x8*)(ab + c * 512 + lane * 8);
            ar = mfma16(av, wr[c], ar);
            az = mfma16(av, wz[c], az);
            bf16x8 wnf = (c < 6) ? *(const bf16x8*)(wlds + (wv * 6 + c) * 512 + lane * 8)
                                 : (c == 6 ? wn6g : wn7g);
            an = mfma16(av, wnf, an);
            if (isfc) {   // rotating wave: FC(h_{t-1}) rides on the same av
                bf16x8 ff = *(const bf16x8*)(fcwl + c * 512 + lane * 8);
                afc = mfma16(av, ff, afc);
            }
        }
        if (isfc && nn == 0) {
            const int s = t - 1;
            f32x4 v;
            #pragma unroll
            for (int m = 0; m < 4; ++m) v[m] = afc[m] + fcb;
            *(f32x4*)(oring + (((s >> 5) & 1) << 9) + ((s & 31) << 4) + q * 4) = v;
        }

        // ---- packed-f32 nonlinearity (pairs m={0,1} and m={2,3}) ----
        short* hw = abuf + nxt * 4096 + koff;
        const f32x2 one2 = {1.f, 1.f};
        #pragma unroll
        for (int p = 0; p < 2; ++p) {
            const int gxp = p ? gx.y : gx.x;
            const int gzp = p ? gz.y : gz.x;
            const int gnp = p ? gn.y : gn.x;
            f32x2 arp = {ar[2*p], ar[2*p+1]};
            f32x2 azp = {az[2*p], az[2*p+1]};
            f32x2 anp = {an[2*p], an[2*p+1]};
            f32x2 hpp = {hp[2*p], hp[2*p+1]};

            f32x2 tr = arp + bfup2(gxp);                    // v_pk_add
            f32x2 tz = azp + bfup2(gzp);
            f32x2 er = {__expf(-tr[0]), __expf(-tr[1])};    // trans (scalar)
            f32x2 ez = {__expf(-tz[0]), __expf(-tz[1])};
            f32x2 dr = er + one2, dz = ez + one2;
            f32x2 rr = {fast_rcp(dr[0]), fast_rcp(dr[1])};
            f32x2 zz = {fast_rcp(dz[0]), fast_rcp(dz[1])};
            f32x2 y  = __builtin_elementwise_fma(rr, anp, bfup2(gnp)); // v_pk_fma
            f32x2 en = {__expf(-2.f*y[0]), __expf(-2.f*y[1])};
            f32x2 dn = en + one2;
            f32x2 qn = {fast_rcp(dn[0]), fast_rcp(dn[1])};
            f32x2 nt = __builtin_elementwise_fma((f32x2){2.f,2.f}, qn,
                                                 (f32x2){-1.f,-1.f}); // 2q-1
            f32x2 df = hpp - nt;                            // v_pk_add(neg)
            f32x2 h2 = __builtin_elementwise_fma(zz, df, nt);
            hp[2*p] = h2[0]; hp[2*p+1] = h2[1];
            const int pk = cvtpk_bf16(h2[0], h2[1]);        // RNE bf16 pair
            hw[(2*p) * 8]     = (short)(pk & 0xffff);
            hw[(2*p + 1) * 8] = (short)(((unsigned)pk) >> 16);
        }
        __syncthreads();   // single per-step barrier
    }

    // ---- tail: FC for step ns-1, flush last 32, h carry ----
    if (wv == 0) {
        const short* ab = abuf + (ns & 1) * 4096;
        f32x4 afc = {0.f, 0.f, 0.f, 0.f};
        #pragma unroll
        for (int c = 0; c < 8; ++c)
            afc = mfma16(*(const bf16x8*)(ab + c * 512 + lane * 8),
                         *(const bf16x8*)(fcwl + c * 512 + lane * 8), afc);
        if (nn == 0) {
            const int s = ns - 1;
            f32x4 v;
            #pragma unroll
            for (int m = 0; m < 4; ++m) v[m] = afc[m] + fcb;
            *(f32x4*)(oring + (((s >> 5) & 1) << 9) + ((s & 31) << 4) + q * 4) = v;
        }
    }
    __syncthreads();
    if (tid < 512) {
        const int s0 = ns - 32;
        out[((size_t)(t0 + s0 + (tid >> 4))) * NB + bbase + (tid & 15)] =
            oring[(((s0 >> 5) & 1) << 9) + (tid >> 4) * 16 + (tid & 15)];
    }
    #pragma unroll
    for (int m = 0; m < 4; ++m)
        hcar[(size_t)(bbase + q * 4 + m) * NH + wv * 16 + nn] = hp[m];
}

extern "C" void kernel_launch(void* const* d_in, const int* in_sizes, int n_in,
                              void* d_out, int out_size, void* d_ws, size_t ws_size,
                              hipStream_t stream) {
    (void)in_sizes; (void)n_in; (void)out_size;
    const float* x    = (const float*)d_in[0];
    const float* w_ih = (const float*)d_in[1];
    const float* w_hh = (const float*)d_in[2];
    const float* b_ih = (const float*)d_in[3];
    const float* b_hh = (const float*)d_in[4];
    const float* fc_w = (const float*)d_in[5];
    const float* fc_b = (const float*)d_in[6];
    float* out  = (float*)d_out;
    float* hcar = (float*)d_ws;                       // 64 KB h carry
    short* wnsc = (short*)((char*)d_ws + 65536);      // 32 KB wn67 bf16 scratch
    short* xg   = (short*)((char*)d_ws + 65536 + 32768);  // 3 gate planes

    const size_t per_step = (size_t)NB * 3 * NH * 2;  // 98304 B / step
    long avail = (long)ws_size - 65536 - 32768;
    int spc = 64;
    if (avail >= (long)per_step * 64) {
        spc = (int)((avail / (long)per_step) / 64) * 64;
        if (spc > SEQ) spc = SEQ;
    }
    for (int t0 = 0; t0 < SEQ; t0 += spc) {
        int ns = (SEQ - t0 < spc) ? (SEQ - t0) : spc;
        size_t plane = (size_t)spc * 16384;           // shorts per gate plane
        xg_pre<<<dim3(2048), dim3(1024), 0, stream>>>(x, w_ih, w_hh, b_ih, b_hh,
                                                      xg, wnsc, plane, t0, ns);
        gru_rec<<<dim3(4), dim3(1024), 0, stream>>>(xg, plane, w_hh, b_hh,
                                                    fc_w, fc_b, wnsc, out, hcar,
                                                    t0, ns);
    }
}